// Round 3
// baseline (168.640 us; speedup 1.0000x reference)
//
#include <hip/hip_runtime.h>
#include <hip/hip_cooperative_groups.h>
#include <math.h>

namespace cg = cooperative_groups;

namespace {

constexpr int K_ = 4;
constexpr int T_ = 1024;
constexpr int B_ = 2;
constexpr int D_ = 256;
constexpr int NSEQ = B_ * D_;        // 512 independent (b,d) sequences

constexpr int CH = 128;              // fine time chunks
constexpr int L_ = T_ / CH;          // 8 steps per chunk
constexpr int LOG_CH = 7;

// ---------------------------------------------------------------------------
// Compile-time-foldable constants: Abar, Bbar (bilinear LegT, N=4, theta=200)
// exactly as the reference builds them, plus AP[s] = Abar^(L*2^s).
// ---------------------------------------------------------------------------
__device__ __forceinline__ void base_consts(float Af[4][4], float Bf[4]) {
    const double dt = 1.0 / 200.0;
    double P[4], A[4][4];
#pragma unroll
    for (int n = 0; n < 4; ++n) P[n] = sqrt(2.0 * n + 1.0);
#pragma unroll
    for (int n = 0; n < 4; ++n)
#pragma unroll
        for (int k = 0; k < 4; ++k) {
            double s = (n >= k) ? 1.0 : (((k - n) & 1) ? -1.0 : 1.0);
            A[n][k] = -P[n] * P[k] * s;
        }
    double aug[4][9];
#pragma unroll
    for (int r = 0; r < 4; ++r) {
#pragma unroll
        for (int c = 0; c < 4; ++c) {
            double idc = (r == c) ? 1.0 : 0.0;
            aug[r][c]     = idc - 0.5 * dt * A[r][c];
            aug[r][4 + c] = idc + 0.5 * dt * A[r][c];
        }
        aug[r][8] = P[r] * dt;
    }
#pragma unroll
    for (int p = 0; p < 4; ++p) {
        double pinv = 1.0 / aug[p][p];
#pragma unroll
        for (int c = 0; c < 9; ++c) aug[p][c] *= pinv;
#pragma unroll
        for (int r = 0; r < 4; ++r) {
            if (r == p) continue;
            double f = aug[r][p];
#pragma unroll
            for (int c = 0; c < 9; ++c) aug[r][c] -= f * aug[p][c];
        }
    }
#pragma unroll
    for (int r = 0; r < 4; ++r) {
#pragma unroll
        for (int c = 0; c < 4; ++c) Af[r][c] = (float)aug[r][4 + c];
        Bf[r] = (float)aug[r][8];
    }
}

__device__ __forceinline__ void matsq(const float X[4][4], float Y[4][4]) {
#pragma unroll
    for (int r = 0; r < 4; ++r)
#pragma unroll
        for (int c = 0; c < 4; ++c) {
            float acc = 0.f;
#pragma unroll
            for (int k = 0; k < 4; ++k) acc = fmaf(X[r][k], X[k][c], acc);
            Y[r][c] = acc;
        }
}

// AP[s] = Abar^(8 * 2^s), s = 0..LOG_CH-1
__device__ __forceinline__ void scan_consts(float AP[LOG_CH][4][4]) {
    float Af[4][4], Bf[4];
    base_consts(Af, Bf);
    float X[4][4], Y[4][4];
    matsq(Af, X);      // A^2
    matsq(X, Y);       // A^4
    matsq(Y, X);       // A^8
#pragma unroll
    for (int s = 0; s < LOG_CH; ++s) {
#pragma unroll
        for (int r = 0; r < 4; ++r)
#pragma unroll
            for (int c = 0; c < 4; ++c) AP[s][r][c] = X[r][c];
        matsq(X, Y);
#pragma unroll
        for (int r = 0; r < 4; ++r)
#pragma unroll
            for (int c = 0; c < 4; ++c) X[r][c] = Y[r][c];
    }
}

// ---------------------------------------------------------------------------
// Fused cooperative kernel: grid = 256 blocks x 256 threads (1 block/CU max,
// trivially co-resident). Phase mapping chosen so each thread's 8 h-values
// (loaded once, coalesced) stay in registers across both grid syncs.
//   phase 1: thread (b,c,d) -> chunk state y[c][seq],  seq = b*256+d
//   phase 2: block -> 2 seqs, Kogge-Stone over 128 chunks in LDS
//   phase 3: thread (b,c,d) -> 8-step recurrence, emit 32 outputs (coalesced)
// ---------------------------------------------------------------------------
__global__ __launch_bounds__(256) void hippo_coop(
    const float* __restrict__ h, const float* __restrict__ M,
    float* __restrict__ ws_y, float* __restrict__ ws_init,
    float* __restrict__ out)
{
    cg::grid_group grid = cg::this_grid();
    const int tid = threadIdx.x;
    const int blk = blockIdx.x;

    __shared__ float4 lds[256];

    // ---- Phase 1: chunk-local end states, h kept in registers ----
    const int d = tid;
    const int c = blk & (CH - 1);
    const int b = blk >> LOG_CH;
    const int seq = b * D_ + d;

    const float* hp = h + ((size_t)(b * T_ + c * L_)) * D_ + d;
    float hv[L_];
#pragma unroll
    for (int i = 0; i < L_; ++i) hv[i] = hp[i * D_];

    {
        float y0 = 0.f, y1 = 0.f, y2 = 0.f, y3 = 0.f;
#pragma unroll
        for (int i = 0; i < L_; ++i) {
            const float* mr = M + (L_ - 1 - i) * K_;  // wave-uniform row
            y0 = fmaf(mr[0], hv[i], y0);
            y1 = fmaf(mr[1], hv[i], y1);
            y2 = fmaf(mr[2], hv[i], y2);
            y3 = fmaf(mr[3], hv[i], y3);
        }
        ((float4*)ws_y)[(size_t)c * NSEQ + seq] = make_float4(y0, y1, y2, y3);
    }
    __threadfence();
    grid.sync();

    // ---- Phase 2: Kogge-Stone scan (2 seqs per block, constant matrices) ----
    {
        float AP[LOG_CH][4][4];
        scan_consts(AP);
        const int sp = tid & 1;
        const int sc = tid >> 1;                 // chunk 0..127
        const int sseq = blk * 2 + sp;
        float4 v = ((const float4*)ws_y)[(size_t)sc * NSEQ + sseq];
#pragma unroll
        for (int s = 0; s < LOG_CH; ++s) {
            const int off = 1 << s;
            lds[tid] = v;
            __syncthreads();
            if (sc >= off) {
                float4 p = lds[tid - off * 2];
                v.x = fmaf(AP[s][0][0], p.x, fmaf(AP[s][0][1], p.y, fmaf(AP[s][0][2], p.z, fmaf(AP[s][0][3], p.w, v.x))));
                v.y = fmaf(AP[s][1][0], p.x, fmaf(AP[s][1][1], p.y, fmaf(AP[s][1][2], p.z, fmaf(AP[s][1][3], p.w, v.y))));
                v.z = fmaf(AP[s][2][0], p.x, fmaf(AP[s][2][1], p.y, fmaf(AP[s][2][2], p.z, fmaf(AP[s][2][3], p.w, v.z))));
                v.w = fmaf(AP[s][3][0], p.x, fmaf(AP[s][3][1], p.y, fmaf(AP[s][3][2], p.z, fmaf(AP[s][3][3], p.w, v.w))));
            }
            __syncthreads();
        }
        float4* ip = (float4*)ws_init;
        if (sc < CH - 1) ip[(size_t)(sc + 1) * NSEQ + sseq] = v;
        if (sc == 0)     ip[sseq] = make_float4(0.f, 0.f, 0.f, 0.f);
    }
    __threadfence();
    grid.sync();

    // ---- Phase 3: recurrence from exclusive init; h already in registers ----
    {
        float Af[4][4], Bf[4];
        base_consts(Af, Bf);
        float4 xi = ((const float4*)ws_init)[(size_t)c * NSEQ + seq];
        float x0 = xi.x, x1 = xi.y, x2 = xi.z, x3 = xi.w;

        float* op = out + ((size_t)(b * T_ + c * L_)) * K_ * D_ + d;
#pragma unroll
        for (int i = 0; i < L_; ++i) {
            float n0 = fmaf(Af[0][0], x0, fmaf(Af[0][1], x1, fmaf(Af[0][2], x2, fmaf(Af[0][3], x3, Bf[0] * hv[i]))));
            float n1 = fmaf(Af[1][0], x0, fmaf(Af[1][1], x1, fmaf(Af[1][2], x2, fmaf(Af[1][3], x3, Bf[1] * hv[i]))));
            float n2 = fmaf(Af[2][0], x0, fmaf(Af[2][1], x1, fmaf(Af[2][2], x2, fmaf(Af[2][3], x3, Bf[2] * hv[i]))));
            float n3 = fmaf(Af[3][0], x0, fmaf(Af[3][1], x1, fmaf(Af[3][2], x2, fmaf(Af[3][3], x3, Bf[3] * hv[i]))));
            x0 = n0; x1 = n1; x2 = n2; x3 = n3;
            op[0 * D_] = x0; op[1 * D_] = x1; op[2 * D_] = x2; op[3 * D_] = x3;
            op += K_ * D_;
        }
    }
}

// ---------------------------------------------------------------------------
// Fallback path (proven in R2) if cooperative launch is rejected.
// ---------------------------------------------------------------------------
__global__ __launch_bounds__(256) void k1a_chunk_states(
    const float* __restrict__ h, const float* __restrict__ M,
    float* __restrict__ ws_y)
{
    const int dlane = threadIdx.x & 63;
    const int csub  = threadIdx.x >> 6;
    const int sg    = blockIdx.x & 7;
    const int cg    = blockIdx.x >> 3;
    const int seq = sg * 64 + dlane;
    const int b = seq >> 8, d = seq & (D_ - 1);
    const int c = cg * 4 + csub;

    const float* hp = h + ((size_t)(b * T_ + c * L_)) * D_ + d;
    float y0 = 0.f, y1 = 0.f, y2 = 0.f, y3 = 0.f;
#pragma unroll
    for (int i = 0; i < L_; ++i) {
        float hvv = hp[i * D_];
        const float* mr = M + (L_ - 1 - i) * K_;
        y0 = fmaf(mr[0], hvv, y0);
        y1 = fmaf(mr[1], hvv, y1);
        y2 = fmaf(mr[2], hvv, y2);
        y3 = fmaf(mr[3], hvv, y3);
    }
    ((float4*)ws_y)[(size_t)c * NSEQ + seq] = make_float4(y0, y1, y2, y3);
}

__global__ __launch_bounds__(256) void k1b_scan(
    const float* __restrict__ ws_y, float* __restrict__ ws_init)
{
    const int sp = threadIdx.x & 1;
    const int c  = threadIdx.x >> 1;
    const int seq = blockIdx.x * 2 + sp;

    float AP[LOG_CH][4][4];
    scan_consts(AP);

    float4 v = ((const float4*)ws_y)[(size_t)c * NSEQ + seq];
    __shared__ float4 lds[CH * 2];
#pragma unroll
    for (int s = 0; s < LOG_CH; ++s) {
        const int off = 1 << s;
        lds[threadIdx.x] = v;
        __syncthreads();
        if (c >= off) {
            float4 p = lds[threadIdx.x - off * 2];
            v.x = fmaf(AP[s][0][0], p.x, fmaf(AP[s][0][1], p.y, fmaf(AP[s][0][2], p.z, fmaf(AP[s][0][3], p.w, v.x))));
            v.y = fmaf(AP[s][1][0], p.x, fmaf(AP[s][1][1], p.y, fmaf(AP[s][1][2], p.z, fmaf(AP[s][1][3], p.w, v.y))));
            v.z = fmaf(AP[s][2][0], p.x, fmaf(AP[s][2][1], p.y, fmaf(AP[s][2][2], p.z, fmaf(AP[s][2][3], p.w, v.z))));
            v.w = fmaf(AP[s][3][0], p.x, fmaf(AP[s][3][1], p.y, fmaf(AP[s][3][2], p.z, fmaf(AP[s][3][3], p.w, v.w))));
        }
        __syncthreads();
    }
    float4* ip = (float4*)ws_init;
    if (c < CH - 1) ip[(size_t)(c + 1) * NSEQ + seq] = v;
    if (c == 0)     ip[seq] = make_float4(0.f, 0.f, 0.f, 0.f);
}

__global__ __launch_bounds__(256) void k2_emit(
    const float* __restrict__ h, const float* __restrict__ ws_init,
    float* __restrict__ out)
{
    const int d = threadIdx.x;
    const int c = blockIdx.x & (CH - 1);
    const int b = blockIdx.x >> LOG_CH;

    float Af[4][4], Bf[4];
    base_consts(Af, Bf);

    float4 xi = ((const float4*)ws_init)[(size_t)c * NSEQ + b * D_ + d];
    float x0 = xi.x, x1 = xi.y, x2 = xi.z, x3 = xi.w;

    const float* hp = h + ((size_t)(b * T_ + c * L_)) * D_ + d;
    float* op = out + ((size_t)(b * T_ + c * L_)) * K_ * D_ + d;
#pragma unroll
    for (int i = 0; i < L_; ++i) {
        float hvv = hp[i * D_];
        float n0 = fmaf(Af[0][0], x0, fmaf(Af[0][1], x1, fmaf(Af[0][2], x2, fmaf(Af[0][3], x3, Bf[0] * hvv))));
        float n1 = fmaf(Af[1][0], x0, fmaf(Af[1][1], x1, fmaf(Af[1][2], x2, fmaf(Af[1][3], x3, Bf[1] * hvv))));
        float n2 = fmaf(Af[2][0], x0, fmaf(Af[2][1], x1, fmaf(Af[2][2], x2, fmaf(Af[2][3], x3, Bf[2] * hvv))));
        float n3 = fmaf(Af[3][0], x0, fmaf(Af[3][1], x1, fmaf(Af[3][2], x2, fmaf(Af[3][3], x3, Bf[3] * hvv))));
        x0 = n0; x1 = n1; x2 = n2; x3 = n3;
        op[0 * D_] = x0; op[1 * D_] = x1; op[2 * D_] = x2; op[3 * D_] = x3;
        op += K_ * D_;
    }
}

} // namespace

extern "C" void kernel_launch(void* const* d_in, const int* in_sizes, int n_in,
                              void* d_out, int out_size, void* d_ws, size_t ws_size,
                              hipStream_t stream) {
    const float* h = (const float*)d_in[0];   // (B, T, D) fp32
    const float* M = (const float*)d_in[1];   // (T, K)    fp32
    float* out = (float*)d_out;               // (B, T, K, D) fp32

    float* ws_y    = (float*)d_ws;                       // [CH][NSEQ][4]
    float* ws_init = ws_y + (size_t)CH * NSEQ * K_;      // [CH][NSEQ][4]

    void* args[] = { (void*)&h, (void*)&M, (void*)&ws_y, (void*)&ws_init,
                     (void*)&out };
    hipError_t err = hipLaunchCooperativeKernel(
        (const void*)hippo_coop, dim3(B_ * CH), dim3(256), args, 0, stream);
    if (err != hipSuccess) {
        // Deterministic fallback: proven 3-kernel path.
        k1a_chunk_states<<<(NSEQ / 64) * (CH / 4), 256, 0, stream>>>(h, M, ws_y);
        k1b_scan<<<NSEQ / 2, 256, 0, stream>>>(ws_y, ws_init);
        k2_emit<<<B_ * CH, 256, 0, stream>>>(h, ws_init, out);
    }
}

// Round 4
// 63.815 us; speedup vs baseline: 2.6426x; 2.6426x over previous
//
#include <hip/hip_runtime.h>
#include <math.h>

namespace {

constexpr int K_ = 4;
constexpr int T_ = 1024;
constexpr int B_ = 2;
constexpr int D_ = 256;
constexpr int NSEQ = B_ * D_;        // 512 independent (b,d) sequences

constexpr int CH = 128;              // fine time chunks
constexpr int L_ = T_ / CH;          // 8 steps per chunk
constexpr int LOG_CH = 7;

// ---------------------------------------------------------------------------
// Compile-time-foldable constants: Abar, Bbar (bilinear LegT, N=4, theta=200)
// exactly as the reference builds them, plus AP[s] = Abar^(L*2^s), s=0..6.
// ---------------------------------------------------------------------------
__device__ __forceinline__ void base_consts(float Af[4][4], float Bf[4]) {
    const double dt = 1.0 / 200.0;
    double P[4], A[4][4];
#pragma unroll
    for (int n = 0; n < 4; ++n) P[n] = sqrt(2.0 * n + 1.0);
#pragma unroll
    for (int n = 0; n < 4; ++n)
#pragma unroll
        for (int k = 0; k < 4; ++k) {
            double s = (n >= k) ? 1.0 : (((k - n) & 1) ? -1.0 : 1.0);
            A[n][k] = -P[n] * P[k] * s;
        }
    double aug[4][9];
#pragma unroll
    for (int r = 0; r < 4; ++r) {
#pragma unroll
        for (int c = 0; c < 4; ++c) {
            double idc = (r == c) ? 1.0 : 0.0;
            aug[r][c]     = idc - 0.5 * dt * A[r][c];
            aug[r][4 + c] = idc + 0.5 * dt * A[r][c];
        }
        aug[r][8] = P[r] * dt;
    }
#pragma unroll
    for (int p = 0; p < 4; ++p) {
        double pinv = 1.0 / aug[p][p];
#pragma unroll
        for (int c = 0; c < 9; ++c) aug[p][c] *= pinv;
#pragma unroll
        for (int r = 0; r < 4; ++r) {
            if (r == p) continue;
            double f = aug[r][p];
#pragma unroll
            for (int c = 0; c < 9; ++c) aug[r][c] -= f * aug[p][c];
        }
    }
#pragma unroll
    for (int r = 0; r < 4; ++r) {
#pragma unroll
        for (int c = 0; c < 4; ++c) Af[r][c] = (float)aug[r][4 + c];
        Bf[r] = (float)aug[r][8];
    }
}

__device__ __forceinline__ void matsq(const float X[4][4], float Y[4][4]) {
#pragma unroll
    for (int r = 0; r < 4; ++r)
#pragma unroll
        for (int c = 0; c < 4; ++c) {
            float acc = 0.f;
#pragma unroll
            for (int k = 0; k < 4; ++k) acc = fmaf(X[r][k], X[k][c], acc);
            Y[r][c] = acc;
        }
}

// AP[s] = Abar^(8 * 2^s), s = 0..LOG_CH-1
__device__ __forceinline__ void scan_consts(float AP[LOG_CH][4][4]) {
    float Af[4][4], Bf[4];
    base_consts(Af, Bf);
    float X[4][4], Y[4][4];
    matsq(Af, X);      // A^2
    matsq(X, Y);       // A^4
    matsq(Y, X);       // A^8
#pragma unroll
    for (int s = 0; s < LOG_CH; ++s) {
#pragma unroll
        for (int r = 0; r < 4; ++r)
#pragma unroll
            for (int c = 0; c < 4; ++c) AP[s][r][c] = X[r][c];
        matsq(X, Y);
#pragma unroll
        for (int r = 0; r < 4; ++r)
#pragma unroll
            for (int c = 0; c < 4; ++c) X[r][c] = Y[r][c];
    }
}

// ---------------------------------------------------------------------------
// k1a: chunk-local end states  y[c][seq] = sum_{i<L} M[L-1-i] * h[c*L+i]
// block = 4 chunks x 64 d-lanes (wave = 64 consecutive d -> 256B coalesced)
// grid  = (NSEQ/64) * (CH/4) = 8 * 32 = 256
// ---------------------------------------------------------------------------
__global__ __launch_bounds__(256) void k1a_chunk_states(
    const float* __restrict__ h, const float* __restrict__ M,
    float* __restrict__ ws_y)
{
    const int dlane = threadIdx.x & 63;
    const int csub  = threadIdx.x >> 6;       // 0..3
    const int sg    = blockIdx.x & 7;         // seq group (64 seqs)
    const int cg    = blockIdx.x >> 3;        // chunk group (4 chunks)
    const int seq = sg * 64 + dlane;
    const int b = seq >> 8, d = seq & (D_ - 1);
    const int c = cg * 4 + csub;

    const float* hp = h + ((size_t)(b * T_ + c * L_)) * D_ + d;
    float y0 = 0.f, y1 = 0.f, y2 = 0.f, y3 = 0.f;
#pragma unroll
    for (int i = 0; i < L_; ++i) {
        float hv = hp[i * D_];
        const float* mr = M + (L_ - 1 - i) * K_;   // wave-uniform row
        y0 = fmaf(mr[0], hv, y0);
        y1 = fmaf(mr[1], hv, y1);
        y2 = fmaf(mr[2], hv, y2);
        y3 = fmaf(mr[3], hv, y3);
    }
    ((float4*)ws_y)[(size_t)c * NSEQ + seq] = make_float4(y0, y1, y2, y3);
}

// ---------------------------------------------------------------------------
// k1b: Kogge-Stone scan across 128 chunks per sequence (constant matrices).
// block = 128 chunks x 2 seqs; grid = NSEQ/2 = 256.
// Writes EXCLUSIVE prefix (chunk-start state) to ws_init[c][seq].
// ---------------------------------------------------------------------------
__global__ __launch_bounds__(256) void k1b_scan(
    const float* __restrict__ ws_y, float* __restrict__ ws_init)
{
    const int sp = threadIdx.x & 1;
    const int c  = threadIdx.x >> 1;          // 0..127
    const int seq = blockIdx.x * 2 + sp;

    float AP[LOG_CH][4][4];
    scan_consts(AP);

    float4 v = ((const float4*)ws_y)[(size_t)c * NSEQ + seq];

    __shared__ float4 lds[CH * 2];
#pragma unroll
    for (int s = 0; s < LOG_CH; ++s) {
        const int off = 1 << s;
        lds[threadIdx.x] = v;
        __syncthreads();
        if (c >= off) {
            float4 p = lds[threadIdx.x - off * 2];
            v.x = fmaf(AP[s][0][0], p.x, fmaf(AP[s][0][1], p.y, fmaf(AP[s][0][2], p.z, fmaf(AP[s][0][3], p.w, v.x))));
            v.y = fmaf(AP[s][1][0], p.x, fmaf(AP[s][1][1], p.y, fmaf(AP[s][1][2], p.z, fmaf(AP[s][1][3], p.w, v.y))));
            v.z = fmaf(AP[s][2][0], p.x, fmaf(AP[s][2][1], p.y, fmaf(AP[s][2][2], p.z, fmaf(AP[s][2][3], p.w, v.z))));
            v.w = fmaf(AP[s][3][0], p.x, fmaf(AP[s][3][1], p.y, fmaf(AP[s][3][2], p.z, fmaf(AP[s][3][3], p.w, v.w))));
        }
        __syncthreads();
    }
    // v = inclusive state after chunk c; init[c+1] = v, init[0] = 0
    float4* ip = (float4*)ws_init;
    if (c < CH - 1) ip[(size_t)(c + 1) * NSEQ + seq] = v;
    if (c == 0)     ip[seq] = make_float4(0.f, 0.f, 0.f, 0.f);
}

// ---------------------------------------------------------------------------
// k2: per-chunk recurrence with proper init; all loads/stores coalesced
// (wave = 64 consecutive d -> 256B segments; h re-read is L2/L3-warm).
// block = 256 threads (one per d); grid = B * CH = 256 blocks.
// ---------------------------------------------------------------------------
__global__ __launch_bounds__(256) void k2_emit(
    const float* __restrict__ h, const float* __restrict__ ws_init,
    float* __restrict__ out)
{
    const int d = threadIdx.x;
    const int c = blockIdx.x & (CH - 1);
    const int b = blockIdx.x >> LOG_CH;

    float Af[4][4], Bf[4];
    base_consts(Af, Bf);

    float4 xi = ((const float4*)ws_init)[(size_t)c * NSEQ + b * D_ + d];
    float x0 = xi.x, x1 = xi.y, x2 = xi.z, x3 = xi.w;

    const float* hp = h + ((size_t)(b * T_ + c * L_)) * D_ + d;
    float* op = out + ((size_t)(b * T_ + c * L_)) * K_ * D_ + d;
#pragma unroll
    for (int i = 0; i < L_; ++i) {
        float hv = hp[i * D_];
        float n0 = fmaf(Af[0][0], x0, fmaf(Af[0][1], x1, fmaf(Af[0][2], x2, fmaf(Af[0][3], x3, Bf[0] * hv))));
        float n1 = fmaf(Af[1][0], x0, fmaf(Af[1][1], x1, fmaf(Af[1][2], x2, fmaf(Af[1][3], x3, Bf[1] * hv))));
        float n2 = fmaf(Af[2][0], x0, fmaf(Af[2][1], x1, fmaf(Af[2][2], x2, fmaf(Af[2][3], x3, Bf[2] * hv))));
        float n3 = fmaf(Af[3][0], x0, fmaf(Af[3][1], x1, fmaf(Af[3][2], x2, fmaf(Af[3][3], x3, Bf[3] * hv))));
        x0 = n0; x1 = n1; x2 = n2; x3 = n3;
        op[0 * D_] = x0; op[1 * D_] = x1; op[2 * D_] = x2; op[3 * D_] = x3;
        op += K_ * D_;
    }
}

} // namespace

extern "C" void kernel_launch(void* const* d_in, const int* in_sizes, int n_in,
                              void* d_out, int out_size, void* d_ws, size_t ws_size,
                              hipStream_t stream) {
    const float* h = (const float*)d_in[0];   // (B, T, D) fp32
    const float* M = (const float*)d_in[1];   // (T, K)    fp32
    float* out = (float*)d_out;               // (B, T, K, D) fp32

    // ws layout: y[CH][NSEQ][4] then init[CH][NSEQ][4]  (1 MiB each)
    float* ws_y    = (float*)d_ws;
    float* ws_init = ws_y + (size_t)CH * NSEQ * K_;

    // NOTE (R3 post-mortem): do NOT fuse these with cooperative grid.sync —
    // on MI355X a 256-block grid.sync + threadfence costs ~45 us each
    // (cross-XCD coherence), vs ~1-2 us per kernel-boundary here.
    k1a_chunk_states<<<(NSEQ / 64) * (CH / 4), 256, 0, stream>>>(h, M, ws_y);
    k1b_scan<<<NSEQ / 2, 256, 0, stream>>>(ws_y, ws_init);
    k2_emit<<<B_ * CH, 256, 0, stream>>>(h, ws_init, out);
}